// Round 6
// baseline (286.334 us; speedup 1.0000x reference)
//
#include <hip/hip_runtime.h>
#include <hip/hip_bf16.h>
#include <stdint.h>

typedef __attribute__((ext_vector_type(8))) short short8;
typedef __attribute__((ext_vector_type(4))) float f32x4;

__device__ __forceinline__ short f2bf(float f) {
  __hip_bfloat16 h = __float2bfloat16(f);  // RNE
  union { __hip_bfloat16 h; unsigned short u; } c;
  c.h = h;
  return (short)c.u;
}
__device__ __forceinline__ short8 cvt8(const float* p) {
  const float4 f0 = *(const float4*)p;
  const float4 f1 = *(const float4*)(p + 4);
  short8 r;
  r[0] = f2bf(f0.x); r[1] = f2bf(f0.y); r[2] = f2bf(f0.z); r[3] = f2bf(f0.w);
  r[4] = f2bf(f1.x); r[5] = f2bf(f1.y); r[6] = f2bf(f1.z); r[7] = f2bf(f1.w);
  return r;
}

// packed weights in d_ws (bf16 bit patterns in shorts):
//   pWin : [3][8K0][8nf][64lane][8]   elems     0 .. 98303
//   pWh  : [3][2][4ks][8nf][64][8]    elems  98304 .. 196607
//   pWout: [3][4K0][16nf][64][8]      elems 196608 .. 294911
__global__ __launch_bounds__(256) void pack_weights(
    const float* __restrict__ Win, const float* __restrict__ Wh,
    const float* __restrict__ Wout, short* __restrict__ o) {
  int gid = blockIdx.x * 256 + threadIdx.x;
  if (gid < 12288) {
    int t = gid / 4096, r = gid % 4096;
    int ks = r / 512, r2 = r % 512, nf = r2 / 64, l = r2 % 64;
    int n = nf * 16 + (l & 15);
    int kb = ks * 32 + (l >> 4) * 8;
#pragma unroll
    for (int i = 0; i < 8; ++i)
      o[gid * 8 + i] = f2bf(Win[(t * 256 + kb + i) * 128 + n]);
  } else if (gid < 24576) {
    int h = gid - 12288;
    int tl = h / 2048, r = h % 2048;
    int ks = r / 512, nf = (r % 512) / 64, l = r % 64;
    int n = nf * 16 + (l & 15);
    int kb = ks * 32 + (l >> 4) * 8;
#pragma unroll
    for (int i = 0; i < 8; ++i)
      o[98304 + h * 8 + i] = f2bf(Wh[(tl * 128 + kb + i) * 128 + n]);
  } else {
    int oo = gid - 24576;
    int t = oo / 4096, r = oo % 4096;
    int ks = r / 1024, nf = (r % 1024) / 64, l = r % 64;
    int n = nf * 16 + (l & 15);
    int kb = ks * 32 + (l >> 4) * 8;
#pragma unroll
    for (int i = 0; i < 8; ++i)
      o[196608 + oo * 8 + i] = f2bf(Wout[(t * 128 + kb + i) * 256 + n]);
  }
}

// One wave = one tower over 32 batch rows. 3 waves/block, 1 barrier/block.
// Single 8KB LDS ping-buffer per wave (in-place layer updates via hoisted
// A-reads; within-wave DS ops are in-order). Tail logits/scores computed in
// fp32 directly from MFMA accumulators (no bf16 x materialization).
__global__ __launch_bounds__(192, 3) void fused_towers(
    const int* __restrict__ user, const int* __restrict__ item,
    const float* __restrict__ su, const float* __restrict__ ti,
    const float* __restrict__ bin, const float* __restrict__ bh,
    const float* __restrict__ bout, const short* __restrict__ wp,
    float* __restrict__ out) {
  __shared__ __align__(16) char Act[3][8192];  // per-wave H buffer: 32 rows x 256B, XOR-swizzled
  __shared__ float sL[3][32];
  __shared__ float sS[3][32];

  const int tid = threadIdx.x;
  const int t = tid >> 6;  // tower = wave id
  const int lane = tid & 63;
  const int ar = lane & 15, g = lane >> 4;
  const int rbase = blockIdx.x * 32;
  const f32x4 fz = {0.f, 0.f, 0.f, 0.f};

  char* const Ha = Act[t];
  const int swzA = (ar & 7) << 4;  // row swizzle for rows ar and 16+ar (same low bits)

  const float* up0 = su + (size_t)user[rbase + ar] * 256;
  const float* up1 = su + (size_t)user[rbase + 16 + ar] * 256;

  f32x4 acc[2][8];

  // ---------- L1: [32x256] @ [256x128] -> Ha ----------
#pragma unroll
  for (int nf = 0; nf < 8; ++nf) { acc[0][nf] = fz; acc[1][nf] = fz; }
#pragma unroll
  for (int K0 = 0; K0 < 8; ++K0) {
    const short8 a0 = cvt8(up0 + K0 * 32 + g * 8);
    const short8 a1 = cvt8(up1 + K0 * 32 + g * 8);
#pragma unroll
    for (int nf = 0; nf < 8; ++nf) {
      const short8 b = *(const short8*)(wp + (size_t)((t * 8 + K0) * 8 + nf) * 512 + lane * 8);
      acc[0][nf] = __builtin_amdgcn_mfma_f32_16x16x32_bf16(a0, b, acc[0][nf], 0, 0, 0);
      acc[1][nf] = __builtin_amdgcn_mfma_f32_16x16x32_bf16(a1, b, acc[1][nf], 0, 0, 0);
    }
  }
#pragma unroll
  for (int m = 0; m < 2; ++m)
#pragma unroll
    for (int nf = 0; nf < 8; ++nf) {
      const int col = nf * 16 + ar;
      const float bv = bin[t * 128 + col];
#pragma unroll
      for (int q = 0; q < 4; ++q) {
        const int r = m * 16 + g * 4 + q;
        const float v = fmaxf(acc[m][nf][q] + bv, 0.f);
        *(short*)(Ha + r * 256 + ((col * 2) ^ ((r & 7) << 4))) = f2bf(v);
      }
    }

  // ---------- L2, L3: [32x128] @ [128x128], in-place in Ha ----------
#pragma unroll
  for (int L = 0; L < 2; ++L) {
    short8 h2[4][2];  // hoist ALL of this wave's Ha reads before in-place writes
#pragma unroll
    for (int ks = 0; ks < 4; ++ks) {
      h2[ks][0] = *(const short8*)(Ha + ar * 256 + ((ks * 64 + g * 16) ^ swzA));
      h2[ks][1] = *(const short8*)(Ha + (16 + ar) * 256 + ((ks * 64 + g * 16) ^ swzA));
    }
#pragma unroll
    for (int nf = 0; nf < 8; ++nf) { acc[0][nf] = fz; acc[1][nf] = fz; }
#pragma unroll
    for (int ks = 0; ks < 4; ++ks)
#pragma unroll
      for (int nf = 0; nf < 8; ++nf) {
        const short8 b = *(const short8*)(wp + 98304 + (size_t)(((t * 2 + L) * 4 + ks) * 8 + nf) * 512 + lane * 8);
        acc[0][nf] = __builtin_amdgcn_mfma_f32_16x16x32_bf16(h2[ks][0], b, acc[0][nf], 0, 0, 0);
        acc[1][nf] = __builtin_amdgcn_mfma_f32_16x16x32_bf16(h2[ks][1], b, acc[1][nf], 0, 0, 0);
      }
#pragma unroll
    for (int m = 0; m < 2; ++m)
#pragma unroll
      for (int nf = 0; nf < 8; ++nf) {
        const int col = nf * 16 + ar;
        const float bv = bh[(t * 2 + L) * 128 + col];
#pragma unroll
        for (int q = 0; q < 4; ++q) {
          const int r = m * 16 + g * 4 + q;
          const float v = fmaxf(acc[m][nf][q] + bv, 0.f);
          *(short*)(Ha + r * 256 + ((col * 2) ^ ((r & 7) << 4))) = f2bf(v);
        }
      }
  }

  // ---------- L4: [32x128] @ [128x256] + fp32 tail from registers ----------
  short8 a4[4][2];
#pragma unroll
  for (int K0 = 0; K0 < 4; ++K0) {
    a4[K0][0] = *(const short8*)(Ha + ar * 256 + ((K0 * 64 + g * 16) ^ swzA));
    a4[K0][1] = *(const short8*)(Ha + (16 + ar) * 256 + ((K0 * 64 + g * 16) ^ swzA));
  }

  float pl[8], ps[8];
#pragma unroll
  for (int i = 0; i < 8; ++i) { pl[i] = 0.f; ps[i] = 0.f; }
  int uid8[8], itm8[8];
#pragma unroll
  for (int m = 0; m < 2; ++m)
#pragma unroll
    for (int q = 0; q < 4; ++q) {
      const int r = m * 16 + g * 4 + q;
      uid8[m * 4 + q] = user[rbase + r];
      itm8[m * 4 + q] = item[rbase + r];
    }

#pragma unroll
  for (int p = 0; p < 2; ++p) {
#pragma unroll
    for (int nf = 0; nf < 8; ++nf) { acc[0][nf] = fz; acc[1][nf] = fz; }
#pragma unroll
    for (int K0 = 0; K0 < 4; ++K0)
#pragma unroll
      for (int nf = 0; nf < 8; ++nf) {
        const short8 b = *(const short8*)(wp + 196608 + (size_t)((t * 4 + K0) * 16 + p * 8 + nf) * 512 + lane * 8);
        acc[0][nf] = __builtin_amdgcn_mfma_f32_16x16x32_bf16(a4[K0][0], b, acc[0][nf], 0, 0, 0);
        acc[1][nf] = __builtin_amdgcn_mfma_f32_16x16x32_bf16(a4[K0][1], b, acc[1][nf], 0, 0, 0);
      }
    float bo8[8];
#pragma unroll
    for (int nf = 0; nf < 8; ++nf) bo8[nf] = bout[t * 256 + p * 128 + nf * 16 + ar];
#pragma unroll
    for (int m = 0; m < 2; ++m)
#pragma unroll
      for (int q = 0; q < 4; ++q) {
        const int i = m * 4 + q;
        const float* kp = ti + (size_t)uid8[i] * 256 + p * 128 + ar;
        const float* ep = ti + (size_t)itm8[i] * 256 + p * 128 + ar;
        float l = pl[i], s = ps[i];
#pragma unroll
        for (int nf = 0; nf < 8; ++nf) {
          const float x = acc[m][nf][q] + bo8[nf];
          l += x * kp[nf * 16];
          s += x * ep[nf * 16];
        }
        pl[i] = l; ps[i] = s;
      }
  }

  // reduce over the 16 ar-lanes of this g-group
#pragma unroll
  for (int i = 0; i < 8; ++i) {
    float a = pl[i], b = ps[i];
#pragma unroll
    for (int off = 1; off < 16; off <<= 1) {
      a += __shfl_xor(a, off);
      b += __shfl_xor(b, off);
    }
    pl[i] = a; ps[i] = b;
  }
  if (ar == 0) {
#pragma unroll
    for (int m = 0; m < 2; ++m)
#pragma unroll
      for (int q = 0; q < 4; ++q) {
        const int r = m * 16 + g * 4 + q;
        sL[t][r] = pl[m * 4 + q];
        sS[t][r] = ps[m * 4 + q];
      }
  }
  __syncthreads();  // the only block-wide barrier

  if (tid < 32) {
    const float l0 = sL[0][tid], l1 = sL[1][tid], l2 = sL[2][tid];
    const float mx = fmaxf(l0, fmaxf(l1, l2));
    const float e0 = __expf(l0 - mx), e1 = __expf(l1 - mx), e2 = __expf(l2 - mx);
    out[rbase + tid] =
        (e0 * sS[0][tid] + e1 * sS[1][tid] + e2 * sS[2][tid]) / (e0 + e1 + e2);
  }
}

extern "C" void kernel_launch(void* const* d_in, const int* in_sizes, int n_in,
                              void* d_out, int out_size, void* d_ws, size_t ws_size,
                              hipStream_t stream) {
  const int* user = (const int*)d_in[0];
  const int* item = (const int*)d_in[1];
  const float* su = (const float*)d_in[2];
  const float* ti = (const float*)d_in[3];
  const float* Win = (const float*)d_in[4];
  const float* bin = (const float*)d_in[5];
  const float* Wh = (const float*)d_in[6];
  const float* bh = (const float*)d_in[7];
  const float* Wout = (const float*)d_in[8];
  const float* bout = (const float*)d_in[9];
  float* out = (float*)d_out;
  short* ws = (short*)d_ws;

  hipLaunchKernelGGL(pack_weights, dim3(144), dim3(256), 0, stream, Win, Wh, Wout, ws);
  hipLaunchKernelGGL(fused_towers, dim3(2048), dim3(192), 0, stream,
                     user, item, su, ti, bin, bh, bout, (const short*)ws, out);
}

// Round 7
// 231.546 us; speedup vs baseline: 1.2366x; 1.2366x over previous
//
#include <hip/hip_runtime.h>
#include <hip/hip_bf16.h>
#include <stdint.h>

typedef __attribute__((ext_vector_type(8))) short short8;
typedef __attribute__((ext_vector_type(4))) float f32x4;

__device__ __forceinline__ short f2bf(float f) {
  __hip_bfloat16 h = __float2bfloat16(f);  // RNE
  union { __hip_bfloat16 h; unsigned short u; } c;
  c.h = h;
  return (short)c.u;
}
__device__ __forceinline__ short8 cvt8(const float* p) {
  const float4 f0 = *(const float4*)p;
  const float4 f1 = *(const float4*)(p + 4);
  short8 r;
  r[0] = f2bf(f0.x); r[1] = f2bf(f0.y); r[2] = f2bf(f0.z); r[3] = f2bf(f0.w);
  r[4] = f2bf(f1.x); r[5] = f2bf(f1.y); r[6] = f2bf(f1.z); r[7] = f2bf(f1.w);
  return r;
}

// packed weights in d_ws (bf16 bit patterns in shorts):
//   pWin : [3][8K0][8nf][64lane][8]   elems     0 .. 98303
//   pWh  : [3][2][4ks][8nf][64][8]    elems  98304 .. 196607
//   pWout: [3][4K0][16nf][64][8]      elems 196608 .. 294911
__global__ __launch_bounds__(256) void pack_weights(
    const float* __restrict__ Win, const float* __restrict__ Wh,
    const float* __restrict__ Wout, short* __restrict__ o) {
  int gid = blockIdx.x * 256 + threadIdx.x;
  if (gid < 12288) {
    int t = gid / 4096, r = gid % 4096;
    int ks = r / 512, r2 = r % 512, nf = r2 / 64, l = r2 % 64;
    int n = nf * 16 + (l & 15);
    int kb = ks * 32 + (l >> 4) * 8;
#pragma unroll
    for (int i = 0; i < 8; ++i)
      o[gid * 8 + i] = f2bf(Win[(t * 256 + kb + i) * 128 + n]);
  } else if (gid < 24576) {
    int h = gid - 12288;
    int tl = h / 2048, r = h % 2048;
    int ks = r / 512, nf = (r % 512) / 64, l = r % 64;
    int n = nf * 16 + (l & 15);
    int kb = ks * 32 + (l >> 4) * 8;
#pragma unroll
    for (int i = 0; i < 8; ++i)
      o[98304 + h * 8 + i] = f2bf(Wh[(tl * 128 + kb + i) * 128 + n]);
  } else {
    int oo = gid - 24576;
    int t = oo / 4096, r = oo % 4096;
    int ks = r / 1024, nf = (r % 1024) / 64, l = r % 64;
    int n = nf * 16 + (l & 15);
    int kb = ks * 32 + (l >> 4) * 8;
#pragma unroll
    for (int i = 0; i < 8; ++i)
      o[196608 + oo * 8 + i] = f2bf(Wout[(t * 128 + kb + i) * 256 + n]);
  }
}

// One wave = one (tower, 16-row group). Block = 384 threads = 6 waves
// (2 row-groups x 3 towers). su rows staged once per block (bf16, swizzled).
// Per-wave private 4KB LDS ping buffer, in-place layer updates via hoisted
// A-reads. Tail logits/scores in fp32 straight from MFMA accumulators.
__global__ __launch_bounds__(384, 3) void fused_towers(
    const int* __restrict__ user, const int* __restrict__ item,
    const float* __restrict__ su, const float* __restrict__ ti,
    const float* __restrict__ bin, const float* __restrict__ bh,
    const float* __restrict__ bout, const short* __restrict__ wp,
    float* __restrict__ out) {
  __shared__ __align__(16) char sA[32 * 512];   // 16KB: 32 su rows, bf16, swizzled
  __shared__ __align__(16) char Act[6][4096];   // per-wave 16 rows x 256B
  __shared__ float sL[3][32];
  __shared__ float sS[3][32];

  const int tid = threadIdx.x;
  const int wid = tid >> 6;
  const int lane = tid & 63;
  const int ar = lane & 15, g = lane >> 4;
  const int rg = wid & 1;        // row-group 0/1
  const int t = wid >> 1;        // tower 0/1/2
  const int rbase = blockIdx.x * 32;
  const f32x4 fz = {0.f, 0.f, 0.f, 0.f};

  // ---------- stage gathered su rows once per block ----------
  for (int c = tid; c < 1024; c += 384) {
    const int row = c >> 5, i = c & 31;
    const float* src = su + (size_t)user[rbase + row] * 256 + i * 8;
    *(short8*)(sA + row * 512 + ((i * 16) ^ ((row & 7) << 4))) = cvt8(src);
  }
  __syncthreads();

  char* const Ha = Act[wid];
  const int swzA = (ar & 7) << 4;   // swizzle bits for LDS rows indexed by ar
  const int rowA = rg * 16 + ar;    // staged-A row this lane reads

  f32x4 acc[8];

  // ---------- L1: [16x256] @ [256x128] -> Ha ----------
#pragma unroll
  for (int nf = 0; nf < 8; ++nf) acc[nf] = fz;
#pragma unroll
  for (int K0 = 0; K0 < 8; ++K0) {
    const short8 a0 = *(const short8*)(sA + rowA * 512 + ((K0 * 64 + g * 16) ^ swzA));
#pragma unroll
    for (int nf = 0; nf < 8; ++nf) {
      const short8 b = *(const short8*)(wp + (size_t)((t * 8 + K0) * 8 + nf) * 512 + lane * 8);
      acc[nf] = __builtin_amdgcn_mfma_f32_16x16x32_bf16(a0, b, acc[nf], 0, 0, 0);
    }
  }
#pragma unroll
  for (int nf = 0; nf < 8; ++nf) {
    const int col = nf * 16 + ar;
    const float bv = bin[t * 128 + col];
#pragma unroll
    for (int q = 0; q < 4; ++q) {
      const int r = g * 4 + q;
      const float v = fmaxf(acc[nf][q] + bv, 0.f);
      *(short*)(Ha + r * 256 + ((col * 2) ^ ((r & 7) << 4))) = f2bf(v);
    }
  }

  // ---------- L2, L3: [16x128] @ [128x128], in-place in Ha ----------
#pragma unroll
  for (int L = 0; L < 2; ++L) {
    short8 h2[4];  // hoist this wave's reads before in-place writes
#pragma unroll
    for (int ks = 0; ks < 4; ++ks)
      h2[ks] = *(const short8*)(Ha + ar * 256 + ((ks * 64 + g * 16) ^ swzA));
#pragma unroll
    for (int nf = 0; nf < 8; ++nf) acc[nf] = fz;
#pragma unroll
    for (int ks = 0; ks < 4; ++ks)
#pragma unroll
      for (int nf = 0; nf < 8; ++nf) {
        const short8 b = *(const short8*)(wp + 98304 + (size_t)(((t * 2 + L) * 4 + ks) * 8 + nf) * 512 + lane * 8);
        acc[nf] = __builtin_amdgcn_mfma_f32_16x16x32_bf16(h2[ks], b, acc[nf], 0, 0, 0);
      }
#pragma unroll
    for (int nf = 0; nf < 8; ++nf) {
      const int col = nf * 16 + ar;
      const float bv = bh[(t * 2 + L) * 128 + col];
#pragma unroll
      for (int q = 0; q < 4; ++q) {
        const int r = g * 4 + q;
        const float v = fmaxf(acc[nf][q] + bv, 0.f);
        *(short*)(Ha + r * 256 + ((col * 2) ^ ((r & 7) << 4))) = f2bf(v);
      }
    }
  }

  // ---------- L4: [16x128] @ [128x256] + fp32 tail from registers ----------
  short8 a4[4];
#pragma unroll
  for (int K0 = 0; K0 < 4; ++K0)
    a4[K0] = *(const short8*)(Ha + ar * 256 + ((K0 * 64 + g * 16) ^ swzA));

  float pl[4], ps[4];
  int uid4[4], itm4[4];
#pragma unroll
  for (int q = 0; q < 4; ++q) {
    pl[q] = 0.f; ps[q] = 0.f;
    const int r = rg * 16 + g * 4 + q;
    uid4[q] = user[rbase + r];
    itm4[q] = item[rbase + r];
  }

#pragma unroll
  for (int p = 0; p < 2; ++p) {
#pragma unroll
    for (int nf = 0; nf < 8; ++nf) acc[nf] = fz;
#pragma unroll
    for (int K0 = 0; K0 < 4; ++K0)
#pragma unroll
      for (int nf = 0; nf < 8; ++nf) {
        const short8 b = *(const short8*)(wp + 196608 + (size_t)((t * 4 + K0) * 16 + p * 8 + nf) * 512 + lane * 8);
        acc[nf] = __builtin_amdgcn_mfma_f32_16x16x32_bf16(a4[K0], b, acc[nf], 0, 0, 0);
      }
    float bo8[8];
#pragma unroll
    for (int nf = 0; nf < 8; ++nf) bo8[nf] = bout[t * 256 + p * 128 + nf * 16 + ar];
#pragma unroll
    for (int q = 0; q < 4; ++q) {
      const float* kp = ti + (size_t)uid4[q] * 256 + p * 128 + ar;
      const float* ep = ti + (size_t)itm4[q] * 256 + p * 128 + ar;
      float l = pl[q], s = ps[q];
#pragma unroll
      for (int nf = 0; nf < 8; ++nf) {
        const float x = acc[nf][q] + bo8[nf];
        l += x * kp[nf * 16];
        s += x * ep[nf * 16];
      }
      pl[q] = l; ps[q] = s;
    }
  }

  // reduce over the 16 ar-lanes of this g-group
#pragma unroll
  for (int q = 0; q < 4; ++q) {
    float a = pl[q], b = ps[q];
#pragma unroll
    for (int off = 1; off < 16; off <<= 1) {
      a += __shfl_xor(a, off);
      b += __shfl_xor(b, off);
    }
    pl[q] = a; ps[q] = b;
  }
  if (ar == 0) {
#pragma unroll
    for (int q = 0; q < 4; ++q) {
      const int r = rg * 16 + g * 4 + q;
      sL[t][r] = pl[q];
      sS[t][r] = ps[q];
    }
  }
  __syncthreads();

  if (tid < 32) {
    const float l0 = sL[0][tid], l1 = sL[1][tid], l2 = sL[2][tid];
    const float mx = fmaxf(l0, fmaxf(l1, l2));
    const float e0 = __expf(l0 - mx), e1 = __expf(l1 - mx), e2 = __expf(l2 - mx);
    out[rbase + tid] =
        (e0 * sS[0][tid] + e1 * sS[1][tid] + e2 * sS[2][tid]) / (e0 + e1 + e2);
  }
}

extern "C" void kernel_launch(void* const* d_in, const int* in_sizes, int n_in,
                              void* d_out, int out_size, void* d_ws, size_t ws_size,
                              hipStream_t stream) {
  const int* user = (const int*)d_in[0];
  const int* item = (const int*)d_in[1];
  const float* su = (const float*)d_in[2];
  const float* ti = (const float*)d_in[3];
  const float* Win = (const float*)d_in[4];
  const float* bin = (const float*)d_in[5];
  const float* Wh = (const float*)d_in[6];
  const float* bh = (const float*)d_in[7];
  const float* Wout = (const float*)d_in[8];
  const float* bout = (const float*)d_in[9];
  float* out = (float*)d_out;
  short* ws = (short*)d_ws;

  hipLaunchKernelGGL(pack_weights, dim3(144), dim3(256), 0, stream, Win, Wh, Wout, ws);
  hipLaunchKernelGGL(fused_towers, dim3(2048), dim3(384), 0, stream,
                     user, item, su, ti, bin, bh, bout, (const short*)ws, out);
}